// Round 10
// baseline (383.744 us; speedup 1.0000x reference)
//
#include <hip/hip_runtime.h>
#include <hip/hip_bf16.h>

// SDPA with materialized attention — single fused kernel, e in LDS, 1024 threads.
// B=16, LQ=LK=2048, D=64. d_out = out [B,LQ,D] f32 then attn [B,LQ,LK] f32.
// Block = 16 q-rows x full k. 16 waves, ~103KB LDS, 1 block/CU (16 waves/CU).
namespace {
constexpr int kB = 16;
constexpr int kLQ = 2048;
constexpr int kLK = 2048;
constexpr int kD = 64;
constexpr float kLog2e = 1.44269504088896340736f;
constexpr int kEStr  = 2056;  // e row stride (shorts): 2048 + 8 -> 16B aligned, 2-way banks
constexpr int kKStrB = 136;   // K/V stage row bytes: 64 bf16 = 128B + 8 pad
constexpr int kMStrB = 264;   // mask stage row bytes: 256 flags + 8 pad
constexpr int kSub = 256;     // k-cols per staged subtile
}

using short8 = __attribute__((ext_vector_type(8))) short;
using f32x4  = __attribute__((ext_vector_type(4))) float;

union S8U { short8 v; unsigned u[4]; unsigned long long q[2]; };

static __device__ __forceinline__ unsigned pk2(float lo, float hi) {
    __hip_bfloat162 h = __float22bfloat162_rn(float2{lo, hi});
    unsigned short a = __builtin_bit_cast(unsigned short, h.x);
    unsigned short b = __builtin_bit_cast(unsigned short, h.y);
    return (unsigned)a | ((unsigned)b << 16);
}
static __device__ __forceinline__ float bf2f(unsigned short s) {
    unsigned u = ((unsigned)s) << 16;
    return __builtin_bit_cast(float, u);
}

__global__ __launch_bounds__(1024, 4) void sdpa_fused16(
    const float* __restrict__ qg, const float* __restrict__ kg,
    const float* __restrict__ vg, const void* __restrict__ maskg,
    float* __restrict__ outg, float* __restrict__ attng)
{
    __shared__ unsigned short s_e[16][kEStr];                    // 64.25 KB
    __shared__ __align__(16) unsigned char s_k[256 * kKStrB];    // 34 KB K/V stage + PV red
    __shared__ __align__(16) unsigned char s_m[16 * kMStrB];     // 4.1 KB mask flags
    __shared__ float s_wsum[16][16];
    __shared__ float s_rinv[16];
    __shared__ int s_flag;

    const int tid = threadIdx.x;
    const int wave = tid >> 6;          // 0..15
    const int lane = tid & 63;
    const int r16 = lane & 15;
    const int g = lane >> 4;

    const int blk = blockIdx.x;
    const int b = blk >> 7;
    const int qt = blk & 127;
    const size_t grow0 = (size_t)b * kLQ + qt * 16;

    // ---- mask dtype detection: int32 0/1 words have bytes 1..3 == 0 ----
    if (tid < 64) {
        unsigned w = ((const unsigned*)maskg)[tid];
        unsigned long long bal = __ballot((w & 0xFFFFFF00u) != 0u);
        if (tid == 0) s_flag = (bal != 0ull) ? 1 : 0;
    }
    __syncthreads();
    const bool mask_byte = (s_flag != 0);
    const unsigned char* mask_u8 = (const unsigned char*)maskg;
    const int* mask_i32 = (const int*)maskg;

    // ---- Q fragment (same 16 rows for every wave), scale folded ----
    short8 q0, q1;
    {
        const float4* qp = (const float4*)(qg + (grow0 + r16) * kD);
        const float s = 0.125f * kLog2e;
        float4 x0 = qp[2*g + 0], x1 = qp[2*g + 1];
        float4 x2 = qp[2*g + 8], x3 = qp[2*g + 9];
        x0 *= s; x1 *= s; x2 *= s; x3 *= s;
        S8U a, c;
        a.u[0] = pk2(x0.x, x0.y); a.u[1] = pk2(x0.z, x0.w);
        a.u[2] = pk2(x1.x, x1.y); a.u[3] = pk2(x1.z, x1.w);
        c.u[0] = pk2(x2.x, x2.y); c.u[1] = pk2(x2.z, x2.w);
        c.u[2] = pk2(x3.x, x3.y); c.u[3] = pk2(x3.z, x3.w);
        q0 = a.v; q1 = c.v;
    }

    // ---- staging indices (coalesced): 256 rows x 64 d per subtile ----
    const int srow = tid >> 2;          // 0..255
    const int sd0  = (tid & 3) * 16;    // d base 0/16/32/48
    const int mrow = tid >> 6;          // 0..15
    const int mc   = (tid & 63) * 4;    // mask col (bytes / flags)
    const size_t kgbase = (size_t)b * kLK * kD;

    // helper lambdas kept manual: prefetch K sub 0 + mask sub 0
    float4 p0, p1, p2, p3;
    unsigned mpre;
    {
        const float* kp = kg + kgbase + (size_t)srow * kD + sd0;
        p0 = *(const float4*)(kp + 0); p1 = *(const float4*)(kp + 4);
        p2 = *(const float4*)(kp + 8); p3 = *(const float4*)(kp + 12);
        if (mask_byte) {
            mpre = *(const unsigned*)(mask_u8 + (grow0 + mrow) * kLK + mc);
        } else {
            const int4 m = *(const int4*)(mask_i32 + (grow0 + mrow) * kLK + mc);
            mpre = (m.x ? 1u : 0u) | (m.y ? 0x100u : 0u) | (m.z ? 0x10000u : 0u) | (m.w ? 0x1000000u : 0u);
        }
    }

    float wsum = 0.f;

    // =================== Phase 1: QK^T + mask + exp2 -> s_e ===================
    for (int sub = 0; sub < kLK / kSub; ++sub) {
        // staged regs -> LDS
        {
            S8U a, c;
            a.u[0] = pk2(p0.x, p0.y); a.u[1] = pk2(p0.z, p0.w);
            a.u[2] = pk2(p1.x, p1.y); a.u[3] = pk2(p1.z, p1.w);
            c.u[0] = pk2(p2.x, p2.y); c.u[1] = pk2(p2.z, p2.w);
            c.u[2] = pk2(p3.x, p3.y); c.u[3] = pk2(p3.z, p3.w);
            *(short8*)(s_k + srow * kKStrB + sd0 * 2) = a.v;
            *(short8*)(s_k + srow * kKStrB + sd0 * 2 + 16) = c.v;
            *(unsigned*)(s_m + mrow * kMStrB + mc) = mpre;
        }
        __syncthreads();

        // prefetch next sub
        if (sub + 1 < kLK / kSub) {
            const int c0n = (sub + 1) * kSub;
            const float* kp = kg + kgbase + (size_t)(c0n + srow) * kD + sd0;
            p0 = *(const float4*)(kp + 0); p1 = *(const float4*)(kp + 4);
            p2 = *(const float4*)(kp + 8); p3 = *(const float4*)(kp + 12);
            if (mask_byte) {
                mpre = *(const unsigned*)(mask_u8 + (grow0 + mrow) * kLK + c0n + mc);
            } else {
                const int4 m = *(const int4*)(mask_i32 + (grow0 + mrow) * kLK + c0n + mc);
                mpre = (m.x ? 1u : 0u) | (m.y ? 0x100u : 0u) | (m.z ? 0x10000u : 0u) | (m.w ? 0x1000000u : 0u);
            }
        }

        // wave w owns cols [sub*256 + w*16, +16)
        const unsigned char* kb = s_k + (wave * 16 + r16) * kKStrB;
        const short8 kA0 = *(const short8*)(kb + g * 16);
        const short8 kA1 = *(const short8*)(kb + 64 + g * 16);
        f32x4 acc = {0.f, 0.f, 0.f, 0.f};
        acc = __builtin_amdgcn_mfma_f32_16x16x32_bf16(kA0, q0, acc, 0, 0, 0);
        acc = __builtin_amdgcn_mfma_f32_16x16x32_bf16(kA1, q1, acc, 0, 0, 0);

        // lane reg r: S[q=r16][sub*256 + wave*16 + 4g + r]
        const unsigned mw = *(const unsigned*)(s_m + r16 * kMStrB + wave * 16 + 4 * g);
        float e4[4];
#pragma unroll
        for (int r = 0; r < 4; ++r)
            e4[r] = ((mw >> (8*r)) & 0xFFu) ? 0.f : __builtin_amdgcn_exp2f(acc[r]);
        wsum += (e4[0] + e4[1]) + (e4[2] + e4[3]);
        const unsigned long long pe = (unsigned long long)pk2(e4[0], e4[1])
                                    | ((unsigned long long)pk2(e4[2], e4[3]) << 32);
        *(unsigned long long*)&s_e[r16][sub * kSub + wave * 16 + 4 * g] = pe;
        __syncthreads();
    }

    // =================== rowsums -> rinv ===================
    wsum += __shfl_xor(wsum, 16, 64);
    wsum += __shfl_xor(wsum, 32, 64);
    if (g == 0) s_wsum[wave][r16] = wsum;
    __syncthreads();
    if (tid < 16) {
        float rs = 0.f;
#pragma unroll
        for (int w = 0; w < 16; ++w) rs += s_wsum[w][tid];
        s_rinv[tid] = __builtin_amdgcn_rcpf(rs);
    }
    __syncthreads();

    // ---- prefetch V sub 0 (latency hidden under attn write) ----
    {
        const float* vp = vg + kgbase + (size_t)srow * kD + sd0;
        p0 = *(const float4*)(vp + 0); p1 = *(const float4*)(vp + 4);
        p2 = *(const float4*)(vp + 8); p3 = *(const float4*)(vp + 12);
    }

    // =================== Phase 2: attn rows (wave w streams row w) ===================
    {
        const int arow = wave;                      // one row per wave
        const float rinv = s_rinv[arow];
        float* ap = attng + (grow0 + arow) * (size_t)kLK;
#pragma unroll
        for (int i = 0; i < 4; ++i) {
            const int col = lane * 8 + i * 512;
            const short8 ev = *(const short8*)&s_e[arow][col];
            f32x4 a0, a1;
            a0[0] = bf2f((unsigned short)ev[0]) * rinv;
            a0[1] = bf2f((unsigned short)ev[1]) * rinv;
            a0[2] = bf2f((unsigned short)ev[2]) * rinv;
            a0[3] = bf2f((unsigned short)ev[3]) * rinv;
            a1[0] = bf2f((unsigned short)ev[4]) * rinv;
            a1[1] = bf2f((unsigned short)ev[5]) * rinv;
            a1[2] = bf2f((unsigned short)ev[6]) * rinv;
            a1[3] = bf2f((unsigned short)ev[7]) * rinv;
            *(f32x4*)(ap + col) = a0;
            *(f32x4*)(ap + col + 4) = a1;
        }
    }
    __syncthreads();   // s_k free (last QK^T reads done), V regs ready to land

    // =================== Phase 3: PV. wave = (kq = w>>2, dt = w&3) ===================
    const int kq = wave >> 2;
    const int d0 = (wave & 3) * 16;
    f32x4 acc = {0.f, 0.f, 0.f, 0.f};

    for (int sub = 0; sub < kLK / kSub; ++sub) {
        // staged V regs -> LDS
        {
            S8U a, c;
            a.u[0] = pk2(p0.x, p0.y); a.u[1] = pk2(p0.z, p0.w);
            a.u[2] = pk2(p1.x, p1.y); a.u[3] = pk2(p1.z, p1.w);
            c.u[0] = pk2(p2.x, p2.y); c.u[1] = pk2(p2.z, p2.w);
            c.u[2] = pk2(p3.x, p3.y); c.u[3] = pk2(p3.z, p3.w);
            *(short8*)(s_k + srow * kKStrB + sd0 * 2) = a.v;
            *(short8*)(s_k + srow * kKStrB + sd0 * 2 + 16) = c.v;
        }
        __syncthreads();

        if (sub + 1 < kLK / kSub) {
            const float* vp = vg + kgbase + (size_t)((sub + 1) * kSub + srow) * kD + sd0;
            p0 = *(const float4*)(vp + 0); p1 = *(const float4*)(vp + 4);
            p2 = *(const float4*)(vp + 8); p3 = *(const float4*)(vp + 12);
        }

        // 2 k-steps over this wave's 64-row quarter
#pragma unroll
        for (int st = 0; st < 2; ++st) {
            const int kb_local = kq * 64 + st * 32 + 8 * g;       // tile-local k row
            const short8 af = *(const short8*)&s_e[r16][sub * kSub + kb_local];
            const unsigned char* vb = s_k + kb_local * kKStrB + (d0 + r16) * 2;
            S8U bv;
            bv.v = short8{
                (short)*(const unsigned short*)(vb + 0 * kKStrB),
                (short)*(const unsigned short*)(vb + 1 * kKStrB),
                (short)*(const unsigned short*)(vb + 2 * kKStrB),
                (short)*(const unsigned short*)(vb + 3 * kKStrB),
                (short)*(const unsigned short*)(vb + 4 * kKStrB),
                (short)*(const unsigned short*)(vb + 5 * kKStrB),
                (short)*(const unsigned short*)(vb + 6 * kKStrB),
                (short)*(const unsigned short*)(vb + 7 * kKStrB) };
            acc = __builtin_amdgcn_mfma_f32_16x16x32_bf16(af, bv.v, acc, 0, 0, 0);
        }
        __syncthreads();
    }

    // ---- 4-way k-reduction in LDS (reuse s_k) + out write ----
    {
        float (*s_red)[16][68] = (float (*)[16][68])s_k;   // [3][16][68] = 13KB < 34KB
        if (kq > 0) {
#pragma unroll
            for (int r = 0; r < 4; ++r) s_red[kq - 1][4 * g + r][d0 + r16] = acc[r];
        }
        __syncthreads();
        if (kq == 0) {
#pragma unroll
            for (int r = 0; r < 4; ++r) {
                const int m = 4 * g + r;
                const float o = acc[r] + s_red[0][m][d0 + r16]
                              + s_red[1][m][d0 + r16] + s_red[2][m][d0 + r16];
                outg[(grow0 + m) * kD + d0 + r16] = o * s_rinv[m];
            }
        }
    }
}

extern "C" void kernel_launch(void* const* d_in, const int* in_sizes, int n_in,
                              void* d_out, int out_size, void* d_ws, size_t ws_size,
                              hipStream_t stream) {
    (void)in_sizes; (void)n_in; (void)out_size; (void)d_ws; (void)ws_size;
    const float* q = (const float*)d_in[0];
    const float* k = (const float*)d_in[1];
    const float* v = (const float*)d_in[2];
    const void* mask = d_in[3];
    float* out = (float*)d_out;
    float* attn = out + (size_t)kB * kLQ * kD;
    sdpa_fused16<<<dim3(kB * 128), 1024, 0, stream>>>(q, k, v, mask, out, attn);
}